// Round 3
// baseline (557.290 us; speedup 1.0000x reference)
//
#include <hip/hip_runtime.h>

// Problem constants (match reference)
#define NN 500000          // nodes
#define FF 128             // feature dim
#define EE 4000000         // edges
#define BB 4               // graphs
#define GG 32              // voxels per dim
#define VV (BB * GG * GG * GG)   // 131072 voxel slots

// d_out layout (flat float32, reference return order)
#define OUT_X    0
#define OUT_POS  (VV * FF)                 // 16,777,216
#define OUT_EIDX (OUT_POS + VV * 3)        // 17,170,432
#define OUT_ATTR (OUT_EIDX + 2 * EE)       // 25,170,432
#define OUT_MASK (OUT_ATTR + 3 * EE)       // 37,170,432

// ---------------------------------------------------------------------------
// Per-node: voxel id + histogram. One fabric atomic per node.
// ---------------------------------------------------------------------------
__global__ __launch_bounds__(256) void vid_kernel(
    const float* __restrict__ pos, const int* __restrict__ batch,
    int* __restrict__ vid, unsigned int* __restrict__ cnt)
{
    int n = blockIdx.x * 256 + threadIdx.x;
    if (n >= NN) return;
    float px = pos[3 * n + 0], py = pos[3 * n + 1], pz = pos[3 * n + 2];
    int vx = min(max((int)floorf(px * 0.125f), 0), GG - 1);
    int vy = min(max((int)floorf(py * 0.125f), 0), GG - 1);
    int vz = min(max((int)floorf(pz * 0.125f), 0), GG - 1);
    int v = batch[n] * (GG * GG * GG) + vx * (GG * GG) + vy * GG + vz;
    vid[n] = v;
    atomicAdd(&cnt[v], 1u);
}

// ---------------------------------------------------------------------------
// 3-pass exclusive scan over cnt[VV] -> offs[VV]; scan_add also packs
// (offs,cnt) into meta[] so pool has a single 8B dependent load.
// ---------------------------------------------------------------------------
__global__ __launch_bounds__(256) void scan_local_kernel(
    const unsigned int* __restrict__ cnt, unsigned int* __restrict__ offs,
    unsigned int* __restrict__ bsum)
{
    __shared__ unsigned int s[256];
    int i = blockIdx.x * 256 + threadIdx.x;
    unsigned int val = cnt[i];
    s[threadIdx.x] = val;
    __syncthreads();
    for (int d = 1; d < 256; d <<= 1) {
        unsigned int t = (threadIdx.x >= d) ? s[threadIdx.x - d] : 0u;
        __syncthreads();
        s[threadIdx.x] += t;
        __syncthreads();
    }
    offs[i] = s[threadIdx.x] - val;              // exclusive
    if (threadIdx.x == 255) bsum[blockIdx.x] = s[255];
}

__global__ __launch_bounds__(512) void scan_bsum_kernel(unsigned int* __restrict__ bsum)
{
    __shared__ unsigned int s[512];
    unsigned int val = bsum[threadIdx.x];
    s[threadIdx.x] = val;
    __syncthreads();
    for (int d = 1; d < 512; d <<= 1) {
        unsigned int t = (threadIdx.x >= d) ? s[threadIdx.x - d] : 0u;
        __syncthreads();
        s[threadIdx.x] += t;
        __syncthreads();
    }
    bsum[threadIdx.x] = s[threadIdx.x] - val;    // exclusive
}

__global__ __launch_bounds__(256) void scan_add_kernel(
    const unsigned int* __restrict__ offs_in, const unsigned int* __restrict__ bsum,
    const unsigned int* __restrict__ cnt,
    unsigned int* __restrict__ cursor, uint2* __restrict__ meta)
{
    int i = blockIdx.x * 256 + threadIdx.x;
    unsigned int o = offs_in[i] + bsum[blockIdx.x];
    cursor[i] = o;
    meta[i] = make_uint2(o, cnt[i]);
}

// ---------------------------------------------------------------------------
// Scatter node ids into CSR order (counting sort placement).
// ---------------------------------------------------------------------------
__global__ __launch_bounds__(256) void scatter_kernel(
    const int* __restrict__ vid, unsigned int* __restrict__ cursor,
    unsigned int* __restrict__ order)
{
    int n = blockIdx.x * 256 + threadIdx.x;
    if (n >= NN) return;
    unsigned int p = atomicAdd(&cursor[vid[n]], 1u);
    order[p] = n;
}

// ---------------------------------------------------------------------------
// One wave per voxel, quarter-split for memory-level parallelism:
//  - (offs,cnt) arrive as ONE uint2 load (meta) — one fewer dependent level.
//  - node indices loaded with one coalesced lane-parallel load, broadcast
//    via __shfl.
//  - 4 groups of 16 lanes; group g reduces nodes k ≡ g (mod 4), covering a
//    full 128-f row as two independent float4 loads. 4 rows in flight/wave.
//  - groups merged with __shfl_xor(16/32).
//  - pos sums fused (butterfly reduce); lane 0 writes pooled_pos AND a
//    16B-padded pos4[] copy so edge_kernel gathers one float4 per endpoint.
// Writes every voxel exactly once (0 for empty) — no memset, no atomics.
// ---------------------------------------------------------------------------
__global__ __launch_bounds__(256) void pool_kernel(
    const float* __restrict__ x, const float* __restrict__ pos,
    const unsigned int* __restrict__ order, const uint2* __restrict__ meta,
    float* __restrict__ out_x, float* __restrict__ out_pos,
    float4* __restrict__ pos4)
{
    int w = threadIdx.x >> 6;          // wave index in block
    int lane = threadIdx.x & 63;
    int g = lane >> 4;                 // group 0..3 (node subset k ≡ g mod 4)
    int fl = lane & 15;                // float4 chunk within group's row halves
    int v = blockIdx.x * 4 + w;
    uint2 mt = meta[v];
    unsigned int start = mt.x;
    unsigned int c = mt.y;

    float4 mlo = make_float4(-INFINITY, -INFINITY, -INFINITY, -INFINITY);
    float4 mhi = mlo;
    float sx = 0.0f, sy = 0.0f, sz = 0.0f;

    for (unsigned int base = 0; base < c; base += 64) {
        unsigned int rem = min(c - base, 64u);
        unsigned int idx = (lane < rem) ? order[start + base + lane] : 0u;
        if (lane < rem) {
            const float* pp = pos + 3 * (size_t)idx;
            sx += pp[0]; sy += pp[1]; sz += pp[2];
        }
        for (unsigned int k = (unsigned int)g; k < rem; k += 4) {
            unsigned int n = __shfl(idx, (int)k);
            const float4* row = (const float4*)(x + (size_t)n * FF);
            float4 a = row[fl];
            float4 b = row[fl + 16];
            mlo.x = fmaxf(mlo.x, a.x); mlo.y = fmaxf(mlo.y, a.y);
            mlo.z = fmaxf(mlo.z, a.z); mlo.w = fmaxf(mlo.w, a.w);
            mhi.x = fmaxf(mhi.x, b.x); mhi.y = fmaxf(mhi.y, b.y);
            mhi.z = fmaxf(mhi.z, b.z); mhi.w = fmaxf(mhi.w, b.w);
        }
    }

    // merge the 4 groups (lanes l, l^16, l^32, l^48 share the same fl)
    #define MERGE(f) f = fmaxf(f, __shfl_xor(f, 16)); f = fmaxf(f, __shfl_xor(f, 32));
    MERGE(mlo.x) MERGE(mlo.y) MERGE(mlo.z) MERGE(mlo.w)
    MERGE(mhi.x) MERGE(mhi.y) MERGE(mhi.z) MERGE(mhi.w)
    #undef MERGE

    float4 res = (lane < 16) ? mlo : mhi;
    if (c == 0) res = make_float4(0.0f, 0.0f, 0.0f, 0.0f);
    if (lane < 32)
        ((float4*)(out_x + (size_t)v * FF))[lane] = res;

    // pos butterfly reduce across all 64 lanes, lane 0 writes mean (twice)
    for (int d = 1; d < 64; d <<= 1) {
        sx += __shfl_xor(sx, d);
        sy += __shfl_xor(sy, d);
        sz += __shfl_xor(sz, d);
    }
    if (lane == 0) {
        float inv = 1.0f / fmaxf((float)c, 1.0f);
        float mx = sx * inv, my = sy * inv, mz = sz * inv;
        out_pos[3 * v + 0] = mx;
        out_pos[3 * v + 1] = my;
        out_pos[3 * v + 2] = mz;
        pos4[v] = make_float4(mx, my, mz, 0.0f);
    }
}

// ---------------------------------------------------------------------------
// Per-edge: remap endpoints, self-loop mask, Cartesian attr.
// 2 edges/thread: int2 loads, float2 stores (8B/lane), one float4 gather per
// endpoint (padded pos4), attr staged via LDS for coalesced writes.
// ---------------------------------------------------------------------------
__global__ __launch_bounds__(256) void edge_kernel(
    const int* __restrict__ eidx, const int* __restrict__ vid,
    const float4* __restrict__ pos4, float* __restrict__ out)
{
    __shared__ float sattr[1536];
    int t = threadIdx.x;
    size_t e0 = (size_t)blockIdx.x * 512;
    int rem = (int)((EE - e0 < 512) ? (EE - e0) : 512);   // 512 or 256 (tail)
    size_t p = e0 / 2 + t;                                // pair index
    float a0x = 0.f, a0y = 0.f, a0z = 0.f, a1x = 0.f, a1y = 0.f, a1z = 0.f;
    if (2 * t < rem) {
        int2 s2 = ((const int2*)eidx)[p];
        int2 d2 = ((const int2*)(eidx + EE))[p];
        int sv0 = vid[s2.x], sv1 = vid[s2.y];
        int dv0 = vid[d2.x], dv1 = vid[d2.y];
        bool m0 = (sv0 != dv0), m1 = (sv1 != dv1);
        ((float2*)(out + OUT_EIDX))[p]      = make_float2((float)sv0, (float)sv1);
        ((float2*)(out + OUT_EIDX + EE))[p] = make_float2((float)dv0, (float)dv1);
        ((float2*)(out + OUT_MASK))[p]      = make_float2(m0 ? 1.f : 0.f, m1 ? 1.f : 0.f);
        if (m0) {
            float4 ps = pos4[sv0], pd = pos4[dv0];
            a0x = (pd.x - ps.x) * 0.0625f + 0.5f;
            a0y = (pd.y - ps.y) * 0.0625f + 0.5f;
            a0z = (pd.z - ps.z) * 0.0625f + 0.5f;
        }
        if (m1) {
            float4 ps = pos4[sv1], pd = pos4[dv1];
            a1x = (pd.x - ps.x) * 0.0625f + 0.5f;
            a1y = (pd.y - ps.y) * 0.0625f + 0.5f;
            a1z = (pd.z - ps.z) * 0.0625f + 0.5f;
        }
    }
    // stride-6 LDS writes (4-way bank alias, ~free); layout = attr[3] per edge
    sattr[6 * t + 0] = a0x; sattr[6 * t + 1] = a0y; sattr[6 * t + 2] = a0z;
    sattr[6 * t + 3] = a1x; sattr[6 * t + 4] = a1y; sattr[6 * t + 5] = a1z;
    __syncthreads();
    float2* dst = (float2*)(out + OUT_ATTR + 3 * e0);
    const float2* sp = (const float2*)sattr;
    int nf2 = 3 * rem / 2;                                // 768 or 384
    #pragma unroll
    for (int i = 0; i < 3; ++i) {
        int idx = i * 256 + t;
        if (idx < nf2) dst[idx] = sp[idx];
    }
}

extern "C" void kernel_launch(void* const* d_in, const int* in_sizes, int n_in,
                              void* d_out, int out_size, void* d_ws, size_t ws_size,
                              hipStream_t stream)
{
    const float* x     = (const float*)d_in[0];
    const float* pos   = (const float*)d_in[1];
    const int*   batch = (const int*)d_in[2];
    const int*   eidx  = (const int*)d_in[3];
    float* out = (float*)d_out;

    // workspace layout (bytes):
    char* ws = (char*)d_ws;
    unsigned int* cnt     = (unsigned int*)(ws + 0);               // VV*4   = 524288
    int*          vid     = (int*)(ws + 524288);                   // NN*4   -> 2524288
    unsigned int* offs    = (unsigned int*)(ws + 2524288);         // VV*4   -> 3048576
    unsigned int* cursor  = (unsigned int*)(ws + 3048576);         // VV*4   -> 3572864
    unsigned int* bsum    = (unsigned int*)(ws + 3572864);         // 512*4  -> 3574912
    unsigned int* order   = (unsigned int*)(ws + 3574912);         // NN*4   -> 5574912
    uint2*        meta    = (uint2*)(ws + 5574912);                // VV*8   -> 6623488
    float4*       pos4    = (float4*)(ws + 6623488);               // VV*16  -> 8720640

    // zero cnt only (512 KB)
    hipMemsetAsync(d_ws, 0, 524288, stream);

    vid_kernel<<<(NN + 255) / 256, 256, 0, stream>>>(pos, batch, vid, cnt);
    scan_local_kernel<<<VV / 256, 256, 0, stream>>>(cnt, offs, bsum);
    scan_bsum_kernel<<<1, 512, 0, stream>>>(bsum);
    scan_add_kernel<<<VV / 256, 256, 0, stream>>>(offs, bsum, cnt, cursor, meta);
    scatter_kernel<<<(NN + 255) / 256, 256, 0, stream>>>(vid, cursor, order);
    pool_kernel<<<VV / 4, 256, 0, stream>>>(x, pos, order, meta,
                                            out + OUT_X, out + OUT_POS, pos4);
    edge_kernel<<<(EE + 511) / 512, 256, 0, stream>>>(eidx, vid, pos4, out);
}